// Round 3
// baseline (7164.230 us; speedup 1.0000x reference)
//
#include <hip/hip_runtime.h>
#include <hip/hip_bf16.h>
#include <stdint.h>

typedef __hip_bfloat16 bf16;
#define DEVI __device__ __forceinline__

constexpr int BATCH = 256;
constexpr int NN    = 81;   // nodes per grid
constexpr int HID   = 96;
constexpr int NE    = 20;   // neighbors per node
constexpr int NOUT  = 9;
constexpr int BLOCK = 512;
constexpr int NB    = 3;    // nodes per pair-block (divides 81)
constexpr int PB    = NB * NE;   // 60 pairs per block
constexpr int CG    = HID / 4;   // 24 col-groups of 4

DEVI float b2f(bf16 x) { return __bfloat162float(x); }
DEVI bf16  f2b(float x) { return __float2bfloat16(x); }
DEVI float sigm(float x) { return 1.f / (1.f + __expf(-x)); }
DEVI float tanh_(float x) { return 1.f - 2.f / (__expf(2.f * x) + 1.f); }

// LDS: everything f32 except the neighbor projection Bv.
// c (LSTM cell) lives in REGISTERS (fixed task mapping) - saves 31KB LDS.
struct Smem {
  float Xg[NN * HID];   // 31104 B  X @ g_w0[:96] + g_b0 (iteration-invariant)
  float h [NN * HID];   // 31104 B  hidden state, f32
  float S1[NN * HID];   // 31104 B  scratch: Msum / g0 / x_in / r1
  float S2[NN * HID];   // 31104 B  scratch: A-proj / M' / g1 / r0
  float t0[PB * HID];   // 23040 B  pair-block staging, f32
  bf16  Bv[NN * HID];   // 15552 B  neighbor projection (only bf16 buffer)
};                      // total 163,008 B <= 163,840 (160 KiB)

DEVI float4 ld4(const float* __restrict__ p) { return *reinterpret_cast<const float4*>(p); }
DEVI void fma4(float a[4], float s, const float4 w) {
  a[0] += s * w.x; a[1] += s * w.y; a[2] += s * w.z; a[3] += s * w.w;
}

// acc[0..3] += dot over K=96 of (LDS f32 row) x (global f32 W cols c4..c4+3, row stride C)
DEVI void dotf4(const float* __restrict__ row, const float* __restrict__ Wc, int C, float acc[4]) {
  #pragma unroll 4
  for (int kk = 0; kk < HID / 4; ++kk) {
    const float4 a = ld4(row + 4 * kk);
    fma4(acc, a.x, ld4(Wc + (4 * kk)     * C));
    fma4(acc, a.y, ld4(Wc + (4 * kk + 1) * C));
    fma4(acc, a.z, ld4(Wc + (4 * kk + 2) * C));
    fma4(acc, a.w, ld4(Wc + (4 * kk + 3) * C));
  }
}

// out[rows x C] = (RELU?)(in[rows x 96] @ W[96 x C] + bias*bscale (+ add))
template<bool RELU, bool ADDIN, bool OUTBF>
DEVI void gemm32(const float* __restrict__ in, int rows,
                 const float* __restrict__ W, int C,
                 const float* __restrict__ bias, float bscale,
                 const float* __restrict__ add,
                 float* __restrict__ outF, bf16* __restrict__ outB, int tid)
{
  const int cg = C >> 2, ntask = rows * cg;
  for (int t = tid; t < ntask; t += BLOCK) {
    const int n = t / cg, c4 = (t - n * cg) << 2;
    float acc[4];
    #pragma unroll
    for (int j = 0; j < 4; ++j) acc[j] = bias ? bias[c4 + j] * bscale : 0.f;
    dotf4(in + n * HID, W + c4, C, acc);
    #pragma unroll
    for (int j = 0; j < 4; ++j) {
      float v = acc[j];
      if (ADDIN) v += add[n * C + c4 + j];
      if (RELU)  v = fmaxf(v, 0.f);
      if (OUTBF) outB[n * C + c4 + j] = f2b(v);
      else       outF[n * C + c4 + j] = v;
    }
  }
}

// e-th Sudoku peer of node n (any enumeration order is fine: the message sum
// is permutation-invariant). 8 row peers, 8 col peers, 4 box-diagonal peers.
DEVI int nbr_of(int n, int e) {
  const int r = n / 9, c = n - 9 * r;
  if (e < 8)  { int cc = c + 1 + e;  if (cc >= 9) cc -= 9; return r * 9 + cc; }
  if (e < 16) { int rr = r + e - 7;  if (rr >= 9) rr -= 9; return rr * 9 + c; }
  const int q = e - 16, dr = 1 + (q >> 1), dc = 1 + (q & 1);
  const int rm = r % 3, cm = c % 3;
  int rr = r - rm + rm + dr; rr -= (rm + dr >= 3) ? 3 : 0;   // r - rm + (rm+dr)%3
  int cc = c - cm + cm + dc; cc -= (cm + dc >= 3) ? 3 : 0;
  return rr * 9 + cc;
}

__global__ __launch_bounds__(BLOCK, 2)
void rrn_kernel(const int* __restrict__ grids, const int* __restrict__ itersp,
                const float* __restrict__ emb,
                const float* __restrict__ in_w0, const float* __restrict__ in_b0,
                const float* __restrict__ in_w1, const float* __restrict__ in_b1,
                const float* __restrict__ in_w2, const float* __restrict__ in_b2,
                const float* __restrict__ rel_w0, const float* __restrict__ rel_b0,
                const float* __restrict__ rel_w1, const float* __restrict__ rel_b1,
                const float* __restrict__ rel_w2, const float* __restrict__ rel_b2,
                const float* __restrict__ g_w0, const float* __restrict__ g_b0,
                const float* __restrict__ g_w1, const float* __restrict__ g_b1,
                const float* __restrict__ g_w2, const float* __restrict__ g_b2,
                const float* __restrict__ wih, const float* __restrict__ whh,
                const float* __restrict__ bih, const float* __restrict__ bhh,
                const float* __restrict__ r_w0, const float* __restrict__ r_b0,
                const float* __restrict__ r_w1, const float* __restrict__ r_b1,
                const float* __restrict__ r_w2, const float* __restrict__ r_b2,
                const float* __restrict__ c0, float* __restrict__ out)
{
  __shared__ Smem s;
  const int b   = blockIdx.x;
  const int tid = threadIdx.x;
  const int iters = itersp[0];

  // ---- LSTM cell state in registers: thread owns tasks t = tid + tc*512 ----
  float creg[4][4];
  #pragma unroll
  for (int tc = 0; tc < 4; ++tc) {
    const int t = tid + tc * BLOCK;
    if (t < NN * CG) {
      const int n = t / CG, c4 = (t - n * CG) << 2;
      #pragma unroll
      for (int j = 0; j < 4; ++j)
        creg[tc][j] = c0[((size_t)b * NN + n) * HID + c4 + j];
    }
  }

  // ---- input MLP layer 0 (K=16, embedding gather) -> S2 ----
  for (int t = tid; t < NN * HID; t += BLOCK) {
    const int n = t / HID, col = t - n * HID;
    const int g = grids[b * NN + n];
    float acc = in_b0[col];
    #pragma unroll
    for (int k = 0; k < 16; ++k)
      acc += emb[g * 16 + k] * in_w0[k * HID + col];
    s.S2[t] = fmaxf(acc, 0.f);
  }
  __syncthreads();
  gemm32<true,  false, false>(s.S2, NN, in_w1, HID, in_b1, 1.f, nullptr, s.S1, nullptr, tid);
  __syncthreads();
  gemm32<false, false, false>(s.S1, NN, in_w2, HID, in_b2, 1.f, nullptr, s.h, nullptr, tid); // h0 = X
  __syncthreads();
  // Xg = X @ g_w0[:96] + g_b0 (iteration-invariant)
  gemm32<false, false, false>(s.h, NN, g_w0, HID, g_b0, 1.f, nullptr, s.Xg, nullptr, tid);
  __syncthreads();

  for (int it = 0; it < iters; ++it) {
    // A = rel_b0 + h @ rel_w0[:96] (f32) ; Bv = h @ rel_w0[96:] (bf16) ; zero Msum
    gemm32<false, false, false>(s.h, NN, rel_w0,             HID, rel_b0, 1.f, nullptr, s.S2, nullptr, tid);
    gemm32<false, false, true >(s.h, NN, rel_w0 + HID * HID, HID, nullptr, 0.f, nullptr, nullptr, s.Bv, tid);
    for (int i = tid; i < NN * HID; i += BLOCK) s.S1[i] = 0.f;
    __syncthreads();

    // ---- pair blocks: 27 x (3 nodes x 20 neighbors) ----
    for (int nb = 0; nb < NN / NB; ++nb) {
      const int n0 = nb * NB;
      // t0 = relu(A[self] + Bv[nbr])   (msg MLP layer 0, restructured)
      for (int t = tid; t < PB * HID; t += BLOCK) {
        const int p = t / HID, col = t - p * HID;
        const int ln = p / NE, e = p - ln * NE;
        const int m = nbr_of(n0 + ln, e);
        s.t0[t] = fmaxf(s.S2[(n0 + ln) * HID + col] + b2f(s.Bv[m * HID + col]), 0.f);
      }
      __syncthreads();
      // h1 = relu(t0 @ rel_w1 + rel_b1), staged in registers then written in-place
      float hreg[3][4];
      #pragma unroll
      for (int tc = 0; tc < 3; ++tc) {
        const int t = tid + tc * BLOCK;
        if (t < PB * CG) {
          const int p = t / CG, c4 = (t - p * CG) << 2;
          float acc[4] = { rel_b1[c4], rel_b1[c4 + 1], rel_b1[c4 + 2], rel_b1[c4 + 3] };
          dotf4(s.t0 + p * HID, rel_w1 + c4, HID, acc);
          #pragma unroll
          for (int j = 0; j < 4; ++j) hreg[tc][j] = fmaxf(acc[j], 0.f);
        }
      }
      __syncthreads();
      #pragma unroll
      for (int tc = 0; tc < 3; ++tc) {
        const int t = tid + tc * BLOCK;
        if (t < PB * CG) {
          const int p = t / CG, c4 = (t - p * CG) << 2;
          #pragma unroll
          for (int j = 0; j < 4; ++j) s.t0[p * HID + c4 + j] = hreg[tc][j];
        }
      }
      __syncthreads();
      // Msum[n] += sum_e h1  (msg layer 2 is linear -> applied once after the sum)
      for (int t = tid; t < NB * HID; t += BLOCK) {
        const int ln = t / HID, col = t - ln * HID;
        float a = 0.f;
        #pragma unroll
        for (int e = 0; e < NE; ++e)
          a += s.t0[(ln * NE + e) * HID + col];
        s.S1[(n0 + ln) * HID + col] += a;
      }
      __syncthreads();
    }

    // M' = Msum @ rel_w2 + 20*rel_b2  -> S2
    gemm32<false, false, false>(s.S1, NN, rel_w2, HID, rel_b2, (float)NE, nullptr, s.S2, nullptr, tid);
    __syncthreads();
    // g0 = relu(Xg + M' @ g_w0[96:])  -> S1   (g_b0 folded into Xg)
    gemm32<true, true, false>(s.S2, NN, g_w0 + HID * HID, HID, nullptr, 0.f, s.Xg, s.S1, nullptr, tid);
    __syncthreads();
    // g1 = relu(g0 @ g_w1 + g_b1)     -> S2
    gemm32<true, false, false>(s.S1, NN, g_w1, HID, g_b1, 1.f, nullptr, s.S2, nullptr, tid);
    __syncthreads();
    // x_in = g1 @ g_w2 + g_b2         -> S1
    gemm32<false, false, false>(s.S2, NN, g_w2, HID, g_b2, 1.f, nullptr, s.S1, nullptr, tid);
    __syncthreads();

    // ---- LSTM cell: gates = x_in @ wih + h @ whh + (bih+bhh) ----
    float h2reg[4][4];
    #pragma unroll
    for (int tc = 0; tc < 4; ++tc) {
      const int t = tid + tc * BLOCK;
      if (t < NN * CG) {
        const int n = t / CG, c4 = (t - n * CG) << 2;
        float gi[4], gf[4], gg[4], go[4];
        #pragma unroll
        for (int j = 0; j < 4; ++j) {
          gi[j] = bih[c4 + j]       + bhh[c4 + j];
          gf[j] = bih[96 + c4 + j]  + bhh[96 + c4 + j];
          gg[j] = bih[192 + c4 + j] + bhh[192 + c4 + j];
          go[j] = bih[288 + c4 + j] + bhh[288 + c4 + j];
        }
        const float* __restrict__ xrow = s.S1 + n * HID;
        const float* __restrict__ hrow = s.h + n * HID;
        #pragma unroll 2
        for (int kk = 0; kk < HID / 4; ++kk) {
          const float4 xv = ld4(xrow + 4 * kk);
          const float4 hv = ld4(hrow + 4 * kk);
          const float xa[4] = { xv.x, xv.y, xv.z, xv.w };
          const float ha[4] = { hv.x, hv.y, hv.z, hv.w };
          #pragma unroll
          for (int d = 0; d < 4; ++d) {
            const float* wi = wih + (4 * kk + d) * 384 + c4;
            const float* wh = whh + (4 * kk + d) * 384 + c4;
            fma4(gi, xa[d], ld4(wi));       fma4(gi, ha[d], ld4(wh));
            fma4(gf, xa[d], ld4(wi + 96));  fma4(gf, ha[d], ld4(wh + 96));
            fma4(gg, xa[d], ld4(wi + 192)); fma4(gg, ha[d], ld4(wh + 192));
            fma4(go, xa[d], ld4(wi + 288)); fma4(go, ha[d], ld4(wh + 288));
          }
        }
        #pragma unroll
        for (int j = 0; j < 4; ++j) {
          const float c2 = sigm(gf[j]) * creg[tc][j] + sigm(gi[j]) * tanh_(gg[j]);
          creg[tc][j] = c2;
          h2reg[tc][j] = sigm(go[j]) * tanh_(c2);
        }
      }
    }
    __syncthreads();
    #pragma unroll
    for (int tc = 0; tc < 4; ++tc) {
      const int t = tid + tc * BLOCK;
      if (t < NN * CG) {
        const int n = t / CG, c4 = (t - n * CG) << 2;
        #pragma unroll
        for (int j = 0; j < 4; ++j) s.h[n * HID + c4 + j] = h2reg[tc][j];
      }
    }
    __syncthreads();

    // ---- readout MLP ----
    gemm32<true, false, false>(s.h,  NN, r_w0, HID, r_b0, 1.f, nullptr, s.S2, nullptr, tid);
    __syncthreads();
    gemm32<true, false, false>(s.S2, NN, r_w1, HID, r_b1, 1.f, nullptr, s.S1, nullptr, tid);
    __syncthreads();
    for (int t = tid; t < NN * NOUT; t += BLOCK) {
      const int n = t / NOUT, col = t - n * NOUT;
      float acc = r_b2[col];
      const float* __restrict__ row = s.S1 + n * HID;
      #pragma unroll 4
      for (int kk = 0; kk < HID / 4; ++kk) {
        const float4 a = ld4(row + 4 * kk);
        acc += a.x * r_w2[(4 * kk)     * NOUT + col];
        acc += a.y * r_w2[(4 * kk + 1) * NOUT + col];
        acc += a.z * r_w2[(4 * kk + 2) * NOUT + col];
        acc += a.w * r_w2[(4 * kk + 3) * NOUT + col];
      }
      out[(((size_t)it * BATCH + b) * NN + n) * NOUT + col] = acc;
    }
    __syncthreads();
  }
}

extern "C" void kernel_launch(void* const* d_in, const int* in_sizes, int n_in,
                              void* d_out, int out_size, void* d_ws, size_t ws_size,
                              hipStream_t stream) {
  (void)in_sizes; (void)n_in; (void)out_size; (void)d_ws; (void)ws_size;
  const int* grids  = (const int*)d_in[0];
  const int* iters  = (const int*)d_in[1];
  const float *emb   = (const float*)d_in[2],
    *in_w0 = (const float*)d_in[3],  *in_b0 = (const float*)d_in[4],
    *in_w1 = (const float*)d_in[5],  *in_b1 = (const float*)d_in[6],
    *in_w2 = (const float*)d_in[7],  *in_b2 = (const float*)d_in[8],
    *rel_w0 = (const float*)d_in[9],  *rel_b0 = (const float*)d_in[10],
    *rel_w1 = (const float*)d_in[11], *rel_b1 = (const float*)d_in[12],
    *rel_w2 = (const float*)d_in[13], *rel_b2 = (const float*)d_in[14],
    *g_w0 = (const float*)d_in[15], *g_b0 = (const float*)d_in[16],
    *g_w1 = (const float*)d_in[17], *g_b1 = (const float*)d_in[18],
    *g_w2 = (const float*)d_in[19], *g_b2 = (const float*)d_in[20],
    *wih = (const float*)d_in[21], *whh = (const float*)d_in[22],
    *bih = (const float*)d_in[23], *bhh = (const float*)d_in[24],
    *r_w0 = (const float*)d_in[25], *r_b0 = (const float*)d_in[26],
    *r_w1 = (const float*)d_in[27], *r_b1 = (const float*)d_in[28],
    *r_w2 = (const float*)d_in[29], *r_b2 = (const float*)d_in[30],
    *c0 = (const float*)d_in[31];
  rrn_kernel<<<dim3(BATCH), dim3(BLOCK), 0, stream>>>(
      grids, iters, emb, in_w0, in_b0, in_w1, in_b1, in_w2, in_b2,
      rel_w0, rel_b0, rel_w1, rel_b1, rel_w2, rel_b2,
      g_w0, g_b0, g_w1, g_b1, g_w2, g_b2,
      wih, whh, bih, bhh,
      r_w0, r_b0, r_w1, r_b1, r_w2, r_b2, c0, (float*)d_out);
}

// Round 5
// 2267.823 us; speedup vs baseline: 3.1591x; 3.1591x over previous
//
#include <hip/hip_runtime.h>
#include <hip/hip_bf16.h>
#include <stdint.h>

typedef __attribute__((ext_vector_type(8))) short short8v;  // MFMA bf16 A/B frag (guide §3)
typedef __attribute__((ext_vector_type(4))) float float4v;  // MFMA C/D frag

#define DEVI __device__ __forceinline__

constexpr int BATCH = 256;
constexpr int NN   = 81;
constexpr int HID  = 96;
constexpr int NOUT = 9;
constexpr int BLOCK = 512;
constexpr int LDA = 100;   // LDS f32 row stride: mult of 4 (16B-aligned rows) + bank rotation

// LDS float offsets (frag-read buffers stride LDA; Xg stride 96). Pad-row frag reads
// (rows 81..95) spill into the NEXT region - harmless finite garbage, C rows masked on write.
constexpr int OFF_H  = 0;
constexpr int OFF_AP = 8100;    // 81*100
constexpr int OFF_BV = 16200;
constexpr int OFF_MS = 24300;
constexpr int OFF_XG = 32400;   // 81*96
constexpr int SMEM_F = 40176;   // 160,704 B <= 163,840

// packed weights in d_ws (shorts). Per matrix: hi tiles [(ct*3+kt)*512 + lane*8 + j],
// lo plane at +ntiles*512. ALL source matrices are [K rows][C cols] row-major.
// rel_w0 / g_w0 are 192x96 (K=192): packed as TWO 96x96 halves (rows 0..95 / 96..191).
constexpr int W_REL0A = 0;       // rel_w0 rows 0..95   (self proj)
constexpr int W_REL0B = 18432;   // rel_w0 rows 96..191 (neighbor proj)
constexpr int W_REL1  = 36864;
constexpr int W_REL2  = 55296;
constexpr int W_G0B   = 73728;   // g_w0 rows 96..191
constexpr int W_G1    = 92160;
constexpr int W_G2    = 110592;
constexpr int W_IH    = 129024;  // 96x384, 72 tiles
constexpr int W_HH    = 202752;
constexpr int W_R0    = 276480;
constexpr int W_R1    = 294912;
constexpr int W_R2    = 313344;  // 96x16 (cols 9..15 zero), 3 tiles
constexpr int W_IN1   = 316416;
constexpr int W_IN2   = 334848;
constexpr int W_G0A   = 353280;  // g_w0 rows 0..95 ; end 371,712 shorts = 743,424 B

DEVI float sigm(float x)  { return 1.f / (1.f + __expf(-x)); }
DEVI float tanh_(float x) { return 1.f - 2.f / (__expf(2.f * x) + 1.f); }

// hi = truncate-to-bf16 (exact residual in f32), lo = RNE-bf16(x - hi): rel err ~2^-15
DEVI short bfhi(float x) { union { float f; unsigned u; } v; v.f = x; return (short)(v.u >> 16); }
DEVI float fromBits(short s) { union { unsigned u; float f; } v; v.u = ((unsigned)(unsigned short)s) << 16; return v.f; }
DEVI short bfrne(float x) {
  union { float f; unsigned u; } v; v.f = x;
  unsigned r = v.u + 0x7fffu + ((v.u >> 16) & 1u);
  return (short)(r >> 16);
}
DEVI void split1(float x, short& h, short& l) { h = bfhi(x); l = bfrne(x - fromBits(h)); }

DEVI void splitFrag(const float* p, short8v& hv, short8v& lv) {
  const float4 a = *reinterpret_cast<const float4*>(p);
  const float4 b = *reinterpret_cast<const float4*>(p + 4);
  short h, l;
  split1(a.x, h, l); hv[0] = h; lv[0] = l;
  split1(a.y, h, l); hv[1] = h; lv[1] = l;
  split1(a.z, h, l); hv[2] = h; lv[2] = l;
  split1(a.w, h, l); hv[3] = h; lv[3] = l;
  split1(b.x, h, l); hv[4] = h; lv[4] = l;
  split1(b.y, h, l); hv[5] = h; lv[5] = l;
  split1(b.z, h, l); hv[6] = h; lv[6] = l;
  split1(b.w, h, l); hv[7] = h; lv[7] = l;
}
// t0 = relu(Ap_row + Bv_row), split
DEVI void splitFragPair(const float* ap, const float* bp, short8v& hv, short8v& lv) {
  const float4 a0 = *reinterpret_cast<const float4*>(ap);
  const float4 a1 = *reinterpret_cast<const float4*>(ap + 4);
  const float4 b0 = *reinterpret_cast<const float4*>(bp);
  const float4 b1 = *reinterpret_cast<const float4*>(bp + 4);
  float v[8] = { a0.x + b0.x, a0.y + b0.y, a0.z + b0.z, a0.w + b0.w,
                 a1.x + b1.x, a1.y + b1.y, a1.z + b1.z, a1.w + b1.w };
  short h, l;
  #pragma unroll
  for (int i = 0; i < 8; ++i) { split1(fmaxf(v[i], 0.f), h, l); hv[i] = h; lv[i] = l; }
}

DEVI float4v mfma3(short8v ah, short8v al, short8v bh, short8v bl, float4v acc) {
  acc = __builtin_amdgcn_mfma_f32_16x16x32_bf16(ah, bh, acc, 0, 0, 0);
  acc = __builtin_amdgcn_mfma_f32_16x16x32_bf16(al, bh, acc, 0, 0, 0);
  acc = __builtin_amdgcn_mfma_f32_16x16x32_bf16(ah, bl, acc, 0, 0, 0);
  return acc;
}

// e-th Sudoku peer of node n (order-free: message sum is permutation-invariant)
DEVI int nbr_of(int n, int e) {
  const int r = n / 9, c = n - 9 * r;
  if (e < 8)  { int cc = c + 1 + e;  if (cc >= 9) cc -= 9; return r * 9 + cc; }
  if (e < 16) { int rr = r + e - 7;  if (rr >= 9) rr -= 9; return rr * 9 + c; }
  const int q = e - 16, dr = 1 + (q >> 1), dc = 1 + (q & 1);
  const int rm = r % 3, cm = c % 3;
  int rr = r - rm + rm + dr; rr -= (rm + dr >= 3) ? 3 : 0;
  int cc = c - cm + cm + dc; cc -= (cm + dc >= 3) ? 3 : 0;
  return rr * 9 + cc;
}

// ---------------- weight pack kernel ----------------
__global__ __launch_bounds__(64)
void pack_kernel(const float* rel_w0, const float* rel_w1, const float* rel_w2,
                 const float* g_w0, const float* g_w1, const float* g_w2,
                 const float* wih, const float* whh,
                 const float* r_w0, const float* r_w1, const float* r_w2,
                 const float* in_w1, const float* in_w2, short* ws)
{
  const int lane = threadIdx.x;
  const int blk = blockIdx.x;
  const int starts[16] = {0,18,36,54,72,90,108,126,198,270,288,306,309,327,345,363};
  int mi = 0;
  while (blk >= starts[mi + 1]) ++mi;
  const int tt = blk - starts[mi];
  const int ntile = starts[mi + 1] - starts[mi];
  const float* src; int C = 96, row0 = 0, off;
  switch (mi) {
    case 0:  src = rel_w0; off = W_REL0A; break;            // rel_w0[0:96]   (192x96!)
    case 1:  src = rel_w0; row0 = 96; off = W_REL0B; break; // rel_w0[96:192]
    case 2:  src = rel_w1; off = W_REL1; break;
    case 3:  src = rel_w2; off = W_REL2; break;
    case 4:  src = g_w0; row0 = 96; off = W_G0B; break;
    case 5:  src = g_w1; off = W_G1; break;
    case 6:  src = g_w2; off = W_G2; break;
    case 7:  src = wih; C = 384; off = W_IH; break;
    case 8:  src = whh; C = 384; off = W_HH; break;
    case 9:  src = r_w0; off = W_R0; break;
    case 10: src = r_w1; off = W_R1; break;
    case 11: src = r_w2; C = 9; off = W_R2; break;
    case 12: src = in_w1; off = W_IN1; break;
    case 13: src = in_w2; off = W_IN2; break;
    default: src = g_w0; off = W_G0A; break;
  }
  const int kt = tt % 3, ct = tt / 3;
  const int q = lane >> 4, r = lane & 15;
  const int c = ct * 16 + r;
  short* hd = ws + off + tt * 512 + lane * 8;
  short* ld = hd + ntile * 512;
  #pragma unroll
  for (int j = 0; j < 8; ++j) {
    const int k = row0 + kt * 32 + q * 8 + j;
    float w = (c < C) ? src[k * C + c] : 0.f;
    short h, l; split1(w, h, l);
    hd[j] = h; ld[j] = l;
  }
}

// ---------------- generic node-GEMM stage: dst[81 x (CT*16)] = act(A[81x96] @ W + ...) ----------------
DEVI void stage96(float* sm, int aOff, const short* WS, int wOff, int wTiles, int CT,
                  const float* bias, float bscale, bool relu, bool xgAdd,
                  float* dst, int dstLD, int wave, int lane)
{
  const int rl = lane & 15, q = lane >> 4;
  const int plane = wTiles * 512;
  for (int t = wave; t < 3 * CT; t += 8) {
    const int rtp = t % 3, ct = t / 3;
    short8v ah[2][3], al[2][3];
    #pragma unroll
    for (int sub = 0; sub < 2; ++sub) {
      const int row = rtp * 32 + sub * 16 + rl;
      const float* ap = &sm[aOff + row * LDA + q * 8];
      #pragma unroll
      for (int kt = 0; kt < 3; ++kt) splitFrag(ap + kt * 32, ah[sub][kt], al[sub][kt]);
    }
    float4v acc0 = {0.f, 0.f, 0.f, 0.f}, acc1 = {0.f, 0.f, 0.f, 0.f};
    #pragma unroll
    for (int kt = 0; kt < 3; ++kt) {
      const short* bp = WS + wOff + (ct * 3 + kt) * 512 + lane * 8;
      const short8v bh = *reinterpret_cast<const short8v*>(bp);
      const short8v bl = *reinterpret_cast<const short8v*>(bp + plane);
      acc0 = mfma3(ah[0][kt], al[0][kt], bh, bl, acc0);
      acc1 = mfma3(ah[1][kt], al[1][kt], bh, bl, acc1);
    }
    const int col = ct * 16 + rl;
    #pragma unroll
    for (int sub = 0; sub < 2; ++sub) {
      #pragma unroll
      for (int j = 0; j < 4; ++j) {
        const int row = rtp * 32 + sub * 16 + q * 4 + j;
        if (row < NN) {
          float v = sub ? acc1[j] : acc0[j];
          if (bias)  v += bias[col] * bscale;
          if (xgAdd) v += sm[OFF_XG + row * 96 + col];
          if (relu)  v = fmaxf(v, 0.f);
          dst[row * dstLD + col] = v;
        }
      }
    }
  }
}

// ---------------- main kernel ----------------
__global__ __launch_bounds__(BLOCK, 2)
void rrn_kernel(const int* __restrict__ grids, const int* __restrict__ itersp,
                const float* __restrict__ emb, const float* __restrict__ in_w0,
                const float* __restrict__ in_b0, const float* __restrict__ in_b1,
                const float* __restrict__ in_b2,
                const float* __restrict__ rel_b0, const float* __restrict__ rel_b1,
                const float* __restrict__ rel_b2,
                const float* __restrict__ g_b0, const float* __restrict__ g_b1,
                const float* __restrict__ g_b2,
                const float* __restrict__ bih, const float* __restrict__ bhh,
                const float* __restrict__ r_b0, const float* __restrict__ r_b1,
                const float* __restrict__ r_b2,
                const float* __restrict__ c0, const short* __restrict__ WS,
                float* __restrict__ out)
{
  __shared__ float sm[SMEM_F];
  const int b = blockIdx.x, tid = threadIdx.x;
  const int wave = tid >> 6, lane = tid & 63;
  const int rl = lane & 15, q = lane >> 4;
  const int iters = itersp[0];

  // LSTM cell state in registers: unit u = wave + ui*8 (u<36): rt=u%6, cc=u/6
  float creg[5][4];
  #pragma unroll
  for (int ui = 0; ui < 5; ++ui) {
    const int u = wave + ui * 8;
    if (u < 36) {
      const int rt = u % 6, cc = u / 6;
      #pragma unroll
      for (int j = 0; j < 4; ++j) {
        const int row = rt * 16 + q * 4 + j, col = cc * 16 + rl;
        creg[ui][j] = (row < NN) ? c0[(size_t)b * NN * HID + row * HID + col] : 0.f;
      }
    }
  }
  float pb1[6];
  #pragma unroll
  for (int ct = 0; ct < 6; ++ct) pb1[ct] = rel_b1[ct * 16 + rl];

  // ---- prologue: embed L0 (VALU, K=16) then MFMA stages ----
  for (int t = tid; t < NN * HID; t += BLOCK) {
    const int n = t / HID, col = t - n * HID;
    const int g = grids[b * NN + n];
    float acc = in_b0[col];
    #pragma unroll
    for (int k = 0; k < 16; ++k) acc += emb[g * 16 + k] * in_w0[k * HID + col];
    sm[OFF_AP + n * LDA + col] = fmaxf(acc, 0.f);
  }
  __syncthreads();
  stage96(sm, OFF_AP, WS, W_IN1, 18, 6, in_b1, 1.f, true,  false, &sm[OFF_BV], LDA, wave, lane);
  __syncthreads();
  stage96(sm, OFF_BV, WS, W_IN2, 18, 6, in_b2, 1.f, false, false, &sm[OFF_H],  LDA, wave, lane);
  __syncthreads();
  stage96(sm, OFF_H,  WS, W_G0A, 18, 6, g_b0,  1.f, false, false, &sm[OFF_XG], 96,  wave, lane);
  __syncthreads();

  for (int it = 0; it < iters; ++it) {
    // phase 1: zero Msum; Ap = h@rel_w0[0:96] + rel_b0 ; Bv = h@rel_w0[96:192]
    for (int i = tid; i < 8100; i += BLOCK) sm[OFF_MS + i] = 0.f;
    stage96(sm, OFF_H, WS, W_REL0A, 18, 6, rel_b0, 1.f, false, false, &sm[OFF_AP], LDA, wave, lane);
    stage96(sm, OFF_H, WS, W_REL0B, 18, 6, nullptr, 0.f, false, false, &sm[OFF_BV], LDA, wave, lane);
    __syncthreads();

    // phase 2: pair GEMM, 26 wave-private groups of 64 pair-rows; Msum via LDS atomics
    for (int g4 = wave; g4 < 26; g4 += 8) {
      short8v ah[4][3], al[4][3];
      #pragma unroll
      for (int sub = 0; sub < 4; ++sub) {
        const int row = g4 * 64 + sub * 16 + rl;
        if (row < 1620) {
          const int n = row / 20, e = row - 20 * n, m = nbr_of(n, e);
          const float* ap = &sm[OFF_AP + n * LDA + q * 8];
          const float* bp = &sm[OFF_BV + m * LDA + q * 8];
          #pragma unroll
          for (int kt = 0; kt < 3; ++kt)
            splitFragPair(ap + kt * 32, bp + kt * 32, ah[sub][kt], al[sub][kt]);
        } else {
          const short8v z = {0,0,0,0,0,0,0,0};
          #pragma unroll
          for (int kt = 0; kt < 3; ++kt) { ah[sub][kt] = z; al[sub][kt] = z; }
        }
      }
      for (int ct = 0; ct < 6; ++ct) {
        short8v bh[3], bl[3];
        #pragma unroll
        for (int kt = 0; kt < 3; ++kt) {
          const short* bp = WS + W_REL1 + (ct * 3 + kt) * 512 + lane * 8;
          bh[kt] = *reinterpret_cast<const short8v*>(bp);
          bl[kt] = *reinterpret_cast<const short8v*>(bp + 18 * 512);
        }
        float4v acc[4] = {{0,0,0,0},{0,0,0,0},{0,0,0,0},{0,0,0,0}};
        #pragma unroll
        for (int sub = 0; sub < 4; ++sub)
          #pragma unroll
          for (int kt = 0; kt < 3; ++kt)
            acc[sub] = mfma3(ah[sub][kt], al[sub][kt], bh[kt], bl[kt], acc[sub]);
        const int col = ct * 16 + rl;
        #pragma unroll
        for (int sub = 0; sub < 4; ++sub) {
          const int r0 = g4 * 64 + sub * 16 + q * 4;  // 4 rows, same node (20%4==0)
          if (r0 < 1620) {
            const int node = r0 / 20;
            float s = 0.f;
            #pragma unroll
            for (int j = 0; j < 4; ++j) s += fmaxf(acc[sub][j] + pb1[ct], 0.f);
            atomicAdd(&sm[OFF_MS + node * LDA + col], s);
          }
        }
      }
    }
    __syncthreads();

    // phase 3..6: M' -> g0 -> g1 -> x_in
    stage96(sm, OFF_MS, WS, W_REL2, 18, 6, rel_b2, 20.f, false, false, &sm[OFF_AP], LDA, wave, lane);
    __syncthreads();
    stage96(sm, OFF_AP, WS, W_G0B, 18, 6, nullptr, 0.f, true, true,  &sm[OFF_BV], LDA, wave, lane);
    __syncthreads();
    stage96(sm, OFF_BV, WS, W_G1, 18, 6, g_b1, 1.f, true,  false, &sm[OFF_AP], LDA, wave, lane);
    __syncthreads();
    stage96(sm, OFF_AP, WS, W_G2, 18, 6, g_b2, 1.f, false, false, &sm[OFF_BV], LDA, wave, lane);
    __syncthreads();

    // phase 7: LSTM gates = x_in@wih + h@whh + (bih+bhh); c in registers
    float h2r[5][4];
    #pragma unroll
    for (int ui = 0; ui < 5; ++ui) {
      const int u = wave + ui * 8;
      if (u < 36) {
        const int rt = u % 6, cc = u / 6;
        const int row = rt * 16 + rl;
        short8v ah[6], al[6];
        #pragma unroll
        for (int kt = 0; kt < 3; ++kt)
          splitFrag(&sm[OFF_BV + row * LDA + kt * 32 + q * 8], ah[kt], al[kt]);
        #pragma unroll
        for (int kt = 3; kt < 6; ++kt)
          splitFrag(&sm[OFF_H + row * LDA + (kt - 3) * 32 + q * 8], ah[kt], al[kt]);
        float4v ga[4] = {{0,0,0,0},{0,0,0,0},{0,0,0,0},{0,0,0,0}};
        #pragma unroll
        for (int gate = 0; gate < 4; ++gate) {
          const int ct = gate * 6 + cc;
          #pragma unroll
          for (int kt = 0; kt < 6; ++kt) {
            const int base = (kt < 3) ? W_IH : W_HH;
            const short* bp = WS + base + (ct * 3 + (kt % 3)) * 512 + lane * 8;
            const short8v bh = *reinterpret_cast<const short8v*>(bp);
            const short8v bl = *reinterpret_cast<const short8v*>(bp + 72 * 512);
            ga[gate] = mfma3(ah[kt], al[kt], bh, bl, ga[gate]);
          }
        }
        const int col = cc * 16 + rl;
        #pragma unroll
        for (int j = 0; j < 4; ++j) {
          const float gi = ga[0][j] + bih[col]       + bhh[col];
          const float gf = ga[1][j] + bih[96 + col]  + bhh[96 + col];
          const float gg = ga[2][j] + bih[192 + col] + bhh[192 + col];
          const float go = ga[3][j] + bih[288 + col] + bhh[288 + col];
          const float c2 = sigm(gf) * creg[ui][j] + sigm(gi) * tanh_(gg);
          creg[ui][j] = c2;
          h2r[ui][j] = sigm(go) * tanh_(c2);
        }
      }
    }
    __syncthreads();
    #pragma unroll
    for (int ui = 0; ui < 5; ++ui) {
      const int u = wave + ui * 8;
      if (u < 36) {
        const int rt = u % 6, cc = u / 6;
        #pragma unroll
        for (int j = 0; j < 4; ++j) {
          const int row = rt * 16 + q * 4 + j, col = cc * 16 + rl;
          if (row < NN) sm[OFF_H + row * LDA + col] = h2r[ui][j];
        }
      }
    }
    __syncthreads();

    // phase 8..10: readout
    stage96(sm, OFF_H,  WS, W_R0, 18, 6, r_b0, 1.f, true, false, &sm[OFF_AP], LDA, wave, lane);
    __syncthreads();
    stage96(sm, OFF_AP, WS, W_R1, 18, 6, r_b1, 1.f, true, false, &sm[OFF_BV], LDA, wave, lane);
    __syncthreads();
    if (wave < 3) {  // r2: 96->16 (9 real cols), 3 row-tile-pairs
      const int rtp = wave;
      short8v ah[2][3], al[2][3];
      #pragma unroll
      for (int sub = 0; sub < 2; ++sub) {
        const int row = rtp * 32 + sub * 16 + rl;
        #pragma unroll
        for (int kt = 0; kt < 3; ++kt)
          splitFrag(&sm[OFF_BV + row * LDA + kt * 32 + q * 8], ah[sub][kt], al[sub][kt]);
      }
      float4v a0 = {0,0,0,0}, a1 = {0,0,0,0};
      #pragma unroll
      for (int kt = 0; kt < 3; ++kt) {
        const short* bp = WS + W_R2 + kt * 512 + lane * 8;
        const short8v bh = *reinterpret_cast<const short8v*>(bp);
        const short8v bl = *reinterpret_cast<const short8v*>(bp + 3 * 512);
        a0 = mfma3(ah[0][kt], al[0][kt], bh, bl, a0);
        a1 = mfma3(ah[1][kt], al[1][kt], bh, bl, a1);
      }
      if (rl < NOUT) {
        float* op = out + ((size_t)it * BATCH + b) * NN * NOUT;
        #pragma unroll
        for (int sub = 0; sub < 2; ++sub)
          #pragma unroll
          for (int j = 0; j < 4; ++j) {
            const int row = rtp * 32 + sub * 16 + q * 4 + j;
            if (row < NN) op[row * NOUT + rl] = (sub ? a1[j] : a0[j]) + r_b2[rl];
          }
      }
    }
    __syncthreads();
  }
}

extern "C" void kernel_launch(void* const* d_in, const int* in_sizes, int n_in,
                              void* d_out, int out_size, void* d_ws, size_t ws_size,
                              hipStream_t stream) {
  (void)in_sizes; (void)n_in; (void)out_size; (void)ws_size;
  const int* grids = (const int*)d_in[0];
  const int* iters = (const int*)d_in[1];
  const float *emb = (const float*)d_in[2],
    *in_w0 = (const float*)d_in[3],  *in_b0 = (const float*)d_in[4],
    *in_w1 = (const float*)d_in[5],  *in_b1 = (const float*)d_in[6],
    *in_w2 = (const float*)d_in[7],  *in_b2 = (const float*)d_in[8],
    *rel_w0 = (const float*)d_in[9],  *rel_b0 = (const float*)d_in[10],
    *rel_w1 = (const float*)d_in[11], *rel_b1 = (const float*)d_in[12],
    *rel_w2 = (const float*)d_in[13], *rel_b2 = (const float*)d_in[14],
    *g_w0 = (const float*)d_in[15], *g_b0 = (const float*)d_in[16],
    *g_w1 = (const float*)d_in[17], *g_b1 = (const float*)d_in[18],
    *g_w2 = (const float*)d_in[19], *g_b2 = (const float*)d_in[20],
    *wih = (const float*)d_in[21], *whh = (const float*)d_in[22],
    *bih = (const float*)d_in[23], *bhh = (const float*)d_in[24],
    *r_w0 = (const float*)d_in[25], *r_b0 = (const float*)d_in[26],
    *r_w1 = (const float*)d_in[27], *r_b1 = (const float*)d_in[28],
    *r_w2 = (const float*)d_in[29], *r_b2 = (const float*)d_in[30],
    *c0 = (const float*)d_in[31];
  (void)in_w1; (void)in_w2;
  short* ws = (short*)d_ws;
  pack_kernel<<<dim3(363), dim3(64), 0, stream>>>(
      rel_w0, rel_w1, rel_w2, g_w0, g_w1, g_w2, wih, whh,
      r_w0, r_w1, r_w2, (const float*)d_in[5], (const float*)d_in[7], ws);
  rrn_kernel<<<dim3(BATCH), dim3(BLOCK), 0, stream>>>(
      grids, iters, emb, in_w0, in_b0, in_b1, in_b2,
      rel_b0, rel_b1, rel_b2, g_b0, g_b1, g_b2,
      bih, bhh, r_b0, r_b1, r_b2, c0, (const short*)ws, (float*)d_out);
}